// Round 3
// baseline (766.267 us; speedup 1.0000x reference)
//
#include <hip/hip_runtime.h>

#define SEQ 8192
#define DIM 768

typedef __attribute__((ext_vector_type(8))) short s16x8;   // 8 x bf16
typedef __attribute__((ext_vector_type(4))) float f32x4;

// RNE float -> bf16
__device__ __forceinline__ unsigned short f2bf(float f) {
  union { float f; unsigned u; } v; v.f = f;
  unsigned r = v.u + 0x7FFFu + ((v.u >> 16) & 1u);
  return (unsigned short)(r >> 16);
}

// async global->LDS 16B copy: lds dest = wave-uniform base + lane*16
__device__ __forceinline__ void gll16(const void* gsrc, void* ldst) {
  __builtin_amdgcn_global_load_lds(
      (__attribute__((address_space(1))) unsigned int*)gsrc,
      (__attribute__((address_space(3))) unsigned int*)ldst, 16, 0, 0);
}

// ---------------- cast kernels ----------------
__global__ void cast_x_kernel(const float* __restrict__ s, unsigned short* __restrict__ d, int n4) {
  int i = blockIdx.x * blockDim.x + threadIdx.x;
  if (i >= n4) return;
  float4 v = ((const float4*)s)[i];
  ushort4 r; r.x = f2bf(v.x); r.y = f2bf(v.y); r.z = f2bf(v.z); r.w = f2bf(v.w);
  ((ushort4*)d)[i] = r;
}

__global__ void cast_w_kernel(const float* __restrict__ a, const float* __restrict__ b,
                              const float* __restrict__ c,
                              unsigned short* __restrict__ da, unsigned short* __restrict__ db,
                              unsigned short* __restrict__ dc, int n4) {
  const float* s = (blockIdx.y == 0) ? a : ((blockIdx.y == 1) ? b : c);
  unsigned short* d = (blockIdx.y == 0) ? da : ((blockIdx.y == 1) ? db : dc);
  int i = blockIdx.x * blockDim.x + threadIdx.x;
  if (i >= n4) return;
  float4 v = ((const float4*)s)[i];
  ushort4 r; r.x = f2bf(v.x); r.y = f2bf(v.y); r.z = f2bf(v.z); r.w = f2bf(v.w);
  ((ushort4*)d)[i] = r;
}

// ---------------- projection GEMM: C[m][n] = sum_k X[m][k]*W[n][k] ----------------
__global__ __launch_bounds__(256, 2)
void proj_kernel(const unsigned short* __restrict__ X,
                 const unsigned short* __restrict__ Wq,
                 const unsigned short* __restrict__ Wk,
                 const unsigned short* __restrict__ Wv,
                 unsigned short* __restrict__ Qb,
                 unsigned short* __restrict__ Kb,
                 unsigned short* __restrict__ Vtb) {
  __shared__ __align__(16) char lds[65536];
  const int tid = threadIdx.x;
  const int lane = tid & 63, wv = tid >> 6;
  const int l15 = lane & 15, l4 = lane >> 4;
  const int mt = blockIdx.x, nt = blockIdx.y, z = blockIdx.z;
  const unsigned short* W = (z == 0) ? Wq : ((z == 1) ? Wk : Wv);

  f32x4 acc[4][4];
#pragma unroll
  for (int i = 0; i < 4; ++i)
#pragma unroll
    for (int j = 0; j < 4; ++j) acc[i][j] = f32x4{0.f, 0.f, 0.f, 0.f};

  auto stage = [&](int kk) {
    char* At = lds + (kk & 1) * 32768;
    char* Bt = At + 16384;
    const int d0 = kk * 64;
#pragma unroll
    for (int i = 0; i < 4; ++i) {
      int s = i * 256 + tid;
      int row = s >> 3, c = (s & 7) ^ (row & 7);
      gll16(X + (long)(mt * 128 + row) * DIM + d0 + c * 8, At + i * 4096 + (wv << 10));
      gll16(W + (long)(nt * 128 + row) * DIM + d0 + c * 8, Bt + i * 4096 + (wv << 10));
    }
  };

  stage(0);
#pragma unroll 1
  for (int kk = 0; kk < 12; ++kk) {
    __syncthreads();
    if (kk + 1 < 12) stage(kk + 1);
    const char* At = lds + (kk & 1) * 32768;
    const char* Bt = At + 16384;
#pragma unroll
    for (int ks = 0; ks < 2; ++ks) {
      const int c = ks * 4 + l4;
      s16x8 a[4], b[4];
#pragma unroll
      for (int mi = 0; mi < 4; ++mi) {
        int row = (wv & 1) * 64 + mi * 16 + l15;
        a[mi] = *(const s16x8*)(At + row * 128 + ((c ^ (row & 7)) << 4));
      }
#pragma unroll
      for (int ni = 0; ni < 4; ++ni) {
        int row = (wv >> 1) * 64 + ni * 16 + l15;
        b[ni] = *(const s16x8*)(Bt + row * 128 + ((c ^ (row & 7)) << 4));
      }
#pragma unroll
      for (int mi = 0; mi < 4; ++mi)
#pragma unroll
        for (int ni = 0; ni < 4; ++ni)
          acc[mi][ni] = __builtin_amdgcn_mfma_f32_16x16x32_bf16(a[mi], b[ni], acc[mi][ni], 0, 0, 0);
    }
  }

#pragma unroll
  for (int mi = 0; mi < 4; ++mi)
#pragma unroll
    for (int ni = 0; ni < 4; ++ni) {
      int row0 = mt * 128 + (wv & 1) * 64 + mi * 16 + l4 * 4;
      int col = nt * 128 + (wv >> 1) * 64 + ni * 16 + l15;
      if (z == 2) {
        ushort4 r;
        r.x = f2bf(acc[mi][ni][0]); r.y = f2bf(acc[mi][ni][1]);
        r.z = f2bf(acc[mi][ni][2]); r.w = f2bf(acc[mi][ni][3]);
        *(ushort4*)(Vtb + (long)col * SEQ + row0) = r;  // V transposed: Vt[col][row]
      } else {
        unsigned short* dst = (z == 0) ? Qb : Kb;
#pragma unroll
        for (int g = 0; g < 4; ++g)
          dst[(long)(row0 + g) * DIM + col] = f2bf(acc[mi][ni][g]);
      }
    }
}

// ---------------- flash attention (R0 skeleton + global-V + single-pass P) ----------------
// BM=64 q rows/block, BN=256 keys/iter, 8 waves. V fragments loaded straight from global
// (Vt layout, key-contiguous); PV phase barrier-free; next-iter QK staging hidden behind PV.
#define SCALE_LOG2E 0.05205878f  // (1/sqrt(768)) * log2(e)

__global__ __launch_bounds__(512, 2)
void flash_kernel(const unsigned short* __restrict__ Q,   // [8192][768] bf16
                  const unsigned short* __restrict__ K,   // [8192][768] bf16
                  const unsigned short* __restrict__ V,   // [768][8192] bf16 (transposed)
                  float* __restrict__ outp,               // part [G][8192][768] or out [8192][768]
                  float* __restrict__ lout,               // [G][8192] (G-split mode)
                  int kv_len, int norm_out) {
  // LDS: QK dbuf 2 x (Q 8KB + K 32KB) = 80KB | P 32KB | l_part [4][64] 1KB
  __shared__ __align__(16) char lds[81920 + 32768 + 1024];
  char* arena = lds;
  char* Pl = lds + 81920;
  float* l_part = (float*)(lds + 81920 + 32768);

  const int tid = threadIdx.x;
  const int lane = tid & 63, wv = tid >> 6;
  const int l15 = lane & 15, l4 = lane >> 4;
  const int qtile = blockIdx.x, split = blockIdx.y;
  const long kv0 = (long)split * kv_len;
  const long qrow0 = (long)qtile * 64;
  const int R = wv & 1;   // S row-half
  const int C = wv >> 1;  // S key-quarter

  f32x4 acc_o[4][6];      // O rows rt*16+l4*4+g, cols wv*96+ct*16+l15
  float acc_lp[8];        // per-lane row-sum partials (rows R*32+rt*16+l4*4+g)
#pragma unroll
  for (int i = 0; i < 4; ++i)
#pragma unroll
    for (int j = 0; j < 6; ++j) acc_o[i][j] = f32x4{0.f, 0.f, 0.f, 0.f};
#pragma unroll
  for (int i = 0; i < 8; ++i) acc_lp[i] = 0.f;

  const int niter = kv_len >> 8;

  // stage one BK=64 slice of Q[64x768] + K[256x768] into buf (r&1)
  auto stageQK = [&](long kbB, int r) {
    char* Qc = arena + (r & 1) * 40960;
    char* Kc = Qc + 8192;
    const int d0 = r * 64;
    {
      int s = tid;
      int row = s >> 3, c = (s & 7) ^ (row & 7);
      gll16(Q + (qrow0 + row) * DIM + d0 + c * 8, Qc + (wv << 10));
    }
#pragma unroll
    for (int i = 0; i < 4; ++i) {
      int s = i * 512 + tid;
      int row = s >> 3, c = (s & 7) ^ (row & 7);
      gll16(K + (kbB + row) * DIM + d0 + c * 8, Kc + i * 8192 + (wv << 10));
    }
  };

  stageQK(kv0, 0);

#pragma unroll 1
  for (int it = 0; it < niter; ++it) {
    const long kb = kv0 + (long)it * 256;

    // ---- QK: S[64x256], per-wave region [32 rows x 64 keys] = 2x4 16x16 tiles ----
    f32x4 acc_s[2][4];
#pragma unroll
    for (int a = 0; a < 2; ++a)
#pragma unroll
      for (int b = 0; b < 4; ++b) acc_s[a][b] = f32x4{0.f, 0.f, 0.f, 0.f};

#pragma unroll 1
    for (int r = 0; r < 12; ++r) {
      __syncthreads();  // round-r loads visible; everyone done with buf r-1
      if (r + 1 < 12) stageQK(kb, r + 1);
      const char* Qc = arena + (r & 1) * 40960;
      const char* Kc = Qc + 8192;
#pragma unroll
      for (int ks = 0; ks < 2; ++ks) {
        const int c = ks * 4 + l4;
        s16x8 af[2], bk[4];
#pragma unroll
        for (int rt = 0; rt < 2; ++rt) {
          int row = R * 32 + rt * 16 + l15;
          af[rt] = *(const s16x8*)(Qc + row * 128 + ((c ^ (row & 7)) << 4));
        }
#pragma unroll
        for (int ct = 0; ct < 4; ++ct) {
          int kr = C * 64 + ct * 16 + l15;
          bk[ct] = *(const s16x8*)(Kc + kr * 128 + ((c ^ (kr & 7)) << 4));
        }
#pragma unroll
        for (int rt = 0; rt < 2; ++rt)
#pragma unroll
          for (int ct = 0; ct < 4; ++ct)
            acc_s[rt][ct] = __builtin_amdgcn_mfma_f32_16x16x32_bf16(af[rt], bk[ct], acc_s[rt][ct], 0, 0, 0);
      }
    }

    // ---- P = exp(s*scale) -> bf16 -> LDS (swizzled [64][256]); per-lane l partials ----
#pragma unroll
    for (int rt = 0; rt < 2; ++rt)
#pragma unroll
      for (int ct = 0; ct < 4; ++ct)
#pragma unroll
        for (int g = 0; g < 4; ++g) {
          float p = exp2f(acc_s[rt][ct][g] * SCALE_LOG2E);
          acc_lp[rt * 4 + g] += p;
          int row = R * 32 + rt * 16 + l4 * 4 + g;
          int col = C * 64 + ct * 16 + l15;
          int pc = col >> 3;
          int pcS = (pc & ~7) | ((pc ^ row) & 7);
          *(unsigned short*)(Pl + row * 512 + (pcS << 4) + ((col & 7) << 1)) = f2bf(p);
        }

    __syncthreads();  // P complete for all waves

    // issue next iter's first QK stage now; it has the whole barrier-free PV to land
    if (it + 1 < niter) stageQK(kb + 256, 0);

    // ---- PV: O[64x768] += P[64x256] @ V; vb straight from global (Vt key-contiguous) ----
    s16x8 vb[2][6];
#pragma unroll
    for (int ct = 0; ct < 6; ++ct)
      vb[0][ct] = *(const s16x8*)(V + (long)(wv * 96 + ct * 16 + l15) * SEQ + kb + l4 * 8);
#pragma unroll 1
    for (int kh = 0; kh < 8; ++kh) {
      if (kh + 1 < 8) {
#pragma unroll
        for (int ct = 0; ct < 6; ++ct)
          vb[(kh + 1) & 1][ct] =
              *(const s16x8*)(V + (long)(wv * 96 + ct * 16 + l15) * SEQ + kb + (kh + 1) * 32 + l4 * 8);
      }
      s16x8 pa[4];
#pragma unroll
      for (int rt = 0; rt < 4; ++rt) {
        int row = rt * 16 + l15;
        int pc = kh * 4 + l4;
        int pcS = (pc & ~7) | ((pc ^ row) & 7);
        pa[rt] = *(const s16x8*)(Pl + row * 512 + (pcS << 4));
      }
#pragma unroll
      for (int ct = 0; ct < 6; ++ct)
#pragma unroll
        for (int rt = 0; rt < 4; ++rt)
          acc_o[rt][ct] =
              __builtin_amdgcn_mfma_f32_16x16x32_bf16(pa[rt], vb[kh & 1][ct], acc_o[rt][ct], 0, 0, 0);
    }
    // no trailing barrier: next iter's round-0 barrier orders P reuse
  }

  // ---- l reduction: butterfly over the 16-lane col groups, combine 4 key-quarters via LDS ----
#pragma unroll
  for (int i = 0; i < 8; ++i) {
    float v = acc_lp[i];
    v += __shfl_xor(v, 1); v += __shfl_xor(v, 2);
    v += __shfl_xor(v, 4); v += __shfl_xor(v, 8);
    acc_lp[i] = v;
  }
  if (l15 == 0) {
#pragma unroll
    for (int rt = 0; rt < 2; ++rt)
#pragma unroll
      for (int g = 0; g < 4; ++g)
        l_part[C * 64 + R * 32 + rt * 16 + l4 * 4 + g] = acc_lp[rt * 4 + g];
  }
  __syncthreads();

  if (!norm_out) {
    if (tid < 64)
      lout[(long)split * SEQ + qrow0 + tid] =
          l_part[tid] + l_part[64 + tid] + l_part[128 + tid] + l_part[192 + tid];
#pragma unroll
    for (int rt = 0; rt < 4; ++rt)
#pragma unroll
      for (int ct = 0; ct < 6; ++ct) {
        int col = wv * 96 + ct * 16 + l15;
#pragma unroll
        for (int g = 0; g < 4; ++g) {
          int row = rt * 16 + l4 * 4 + g;
          outp[(long)split * SEQ * DIM + (qrow0 + row) * DIM + col] = acc_o[rt][ct][g];
        }
      }
  } else {
    float linv[4][4];
#pragma unroll
    for (int rt = 0; rt < 4; ++rt)
#pragma unroll
      for (int g = 0; g < 4; ++g) {
        int row = rt * 16 + l4 * 4 + g;
        linv[rt][g] = 1.0f / (l_part[row] + l_part[64 + row] + l_part[128 + row] + l_part[192 + row]);
      }
#pragma unroll
    for (int rt = 0; rt < 4; ++rt)
#pragma unroll
      for (int ct = 0; ct < 6; ++ct) {
        int col = wv * 96 + ct * 16 + l15;
#pragma unroll
        for (int g = 0; g < 4; ++g) {
          int row = rt * 16 + l4 * 4 + g;
          outp[(qrow0 + row) * DIM + col] = acc_o[rt][ct][g] * linv[rt][g];
        }
      }
  }
}

// ---------------- combine (G=2): out = (p0+p1)/(l0+l1) ----------------
__global__ void combine_kernel(const float* __restrict__ part, const float* __restrict__ lsum,
                               float* __restrict__ out, int n4) {
  int i = blockIdx.x * blockDim.x + threadIdx.x;
  if (i >= n4) return;
  int row = (i * 4) / DIM;
  float4 p0 = ((const float4*)part)[i];
  float4 p1 = ((const float4*)(part + (long)SEQ * DIM))[i];
  float inv = 1.0f / (lsum[row] + lsum[SEQ + row]);
  float4 o;
  o.x = (p0.x + p1.x) * inv; o.y = (p0.y + p1.y) * inv;
  o.z = (p0.z + p1.z) * inv; o.w = (p0.w + p1.w) * inv;
  ((float4*)out)[i] = o;
}

// ---------------- host ----------------
extern "C" void kernel_launch(void* const* d_in, const int* in_sizes, int n_in,
                              void* d_out, int out_size, void* d_ws, size_t ws_size,
                              hipStream_t stream) {
  const float* x = (const float*)d_in[0];
  const float* wq = (const float*)d_in[1];
  const float* wk = (const float*)d_in[2];
  const float* wv = (const float*)d_in[3];
  float* out = (float*)d_out;
  char* ws = (char*)d_ws;

  const size_t o_xbf = 0;
  const size_t o_wq = o_xbf + (size_t)SEQ * DIM * 2;
  const size_t o_wk = o_wq + (size_t)DIM * DIM * 2;
  const size_t o_wv = o_wk + (size_t)DIM * DIM * 2;
  const size_t o_q = o_wv + (size_t)DIM * DIM * 2;
  const size_t o_k = o_q + (size_t)SEQ * DIM * 2;
  const size_t o_vt = o_k + (size_t)SEQ * DIM * 2;
  const size_t o_part = o_vt + (size_t)SEQ * DIM * 2;
  const size_t o_l = o_part + (size_t)2 * SEQ * DIM * 4;
  const size_t total_g2 = o_l + (size_t)2 * SEQ * 4;

  unsigned short* Xbf = (unsigned short*)(ws + o_xbf);
  unsigned short* Wqb = (unsigned short*)(ws + o_wq);
  unsigned short* Wkb = (unsigned short*)(ws + o_wk);
  unsigned short* Wvb = (unsigned short*)(ws + o_wv);
  unsigned short* Qb = (unsigned short*)(ws + o_q);
  unsigned short* Kb = (unsigned short*)(ws + o_k);
  unsigned short* Vtb = (unsigned short*)(ws + o_vt);
  float* part = (float*)(ws + o_part);
  float* lbuf = (float*)(ws + o_l);

  const int G = (ws_size >= total_g2) ? 2 : 1;

  cast_x_kernel<<<6144, 256, 0, stream>>>(x, Xbf, SEQ * DIM / 4);
  cast_w_kernel<<<dim3(576, 3), 256, 0, stream>>>(wq, wk, wv, Wqb, Wkb, Wvb, DIM * DIM / 4);
  proj_kernel<<<dim3(64, 6, 3), 256, 0, stream>>>(Xbf, Wqb, Wkb, Wvb, Qb, Kb, Vtb);
  if (G == 2) {
    flash_kernel<<<dim3(128, 2), 512, 0, stream>>>(Qb, Kb, Vtb, part, lbuf, SEQ / 2, 0);
    combine_kernel<<<6144, 256, 0, stream>>>(part, lbuf, out, SEQ * DIM / 4);
  } else {
    flash_kernel<<<dim3(128, 1), 512, 0, stream>>>(Qb, Kb, Vtb, out, nullptr, SEQ, 1);
  }
}

// Round 6
// 391.458 us; speedup vs baseline: 1.9575x; 1.9575x over previous
//
#include <hip/hip_runtime.h>

#define SEQ 8192
#define DIM 768

typedef __attribute__((ext_vector_type(8))) short s16x8;   // 8 x bf16
typedef __attribute__((ext_vector_type(4))) float f32x4;

// RNE float -> bf16
__device__ __forceinline__ unsigned short f2bf(float f) {
  union { float f; unsigned u; } v; v.f = f;
  unsigned r = v.u + 0x7FFFu + ((v.u >> 16) & 1u);
  return (unsigned short)(r >> 16);
}

__device__ __forceinline__ float bf2f(unsigned short s) {
  union { unsigned u; float f; } v; v.u = ((unsigned)s) << 16;
  return v.f;
}

// async global->LDS 16B copy: lds dest = wave-uniform base + lane*16
__device__ __forceinline__ void gll16(const void* gsrc, void* ldst) {
  __builtin_amdgcn_global_load_lds(
      (__attribute__((address_space(1))) unsigned int*)gsrc,
      (__attribute__((address_space(3))) unsigned int*)ldst, 16, 0, 0);
}

// ---------------- fused cast kernel: x (6144 blocks) + wq/wk/wv (576 each) ----------------
#define XN4 (SEQ * DIM / 4)     // 1572864
#define WN4 (DIM * DIM / 4)     // 147456

__global__ void cast_all_kernel(const float* __restrict__ x, const float* __restrict__ wq,
                                const float* __restrict__ wk, const float* __restrict__ wv,
                                unsigned short* __restrict__ dx, unsigned short* __restrict__ dq,
                                unsigned short* __restrict__ dk, unsigned short* __restrict__ dv) {
  int i = blockIdx.x * blockDim.x + threadIdx.x;
  const float* s;
  unsigned short* d;
  int off;
  if (i < XN4) {
    s = x; d = dx; off = i;
  } else {
    int j = i - XN4;
    int wi = j / WN4;
    off = j - wi * WN4;
    s = (wi == 0) ? wq : ((wi == 1) ? wk : wv);
    d = (wi == 0) ? dq : ((wi == 1) ? dk : dv);
  }
  float4 v = ((const float4*)s)[off];
  ushort4 r; r.x = f2bf(v.x); r.y = f2bf(v.y); r.z = f2bf(v.z); r.w = f2bf(v.w);
  ((ushort4*)d)[off] = r;
}

// ---------------- projection GEMM: C[m][n] = sum_k X[m][k]*W[n][k] ----------------
__global__ __launch_bounds__(256, 2)
void proj_kernel(const unsigned short* __restrict__ X,
                 const unsigned short* __restrict__ Wq,
                 const unsigned short* __restrict__ Wk,
                 const unsigned short* __restrict__ Wv,
                 unsigned short* __restrict__ Qb,
                 unsigned short* __restrict__ Kb,
                 unsigned short* __restrict__ Vtb) {
  __shared__ __align__(16) char lds[65536];
  const int tid = threadIdx.x;
  const int lane = tid & 63, wv = tid >> 6;
  const int l15 = lane & 15, l4 = lane >> 4;
  const int mt = blockIdx.x, nt = blockIdx.y, z = blockIdx.z;
  const unsigned short* W = (z == 0) ? Wq : ((z == 1) ? Wk : Wv);

  f32x4 acc[4][4];
#pragma unroll
  for (int i = 0; i < 4; ++i)
#pragma unroll
    for (int j = 0; j < 4; ++j) acc[i][j] = f32x4{0.f, 0.f, 0.f, 0.f};

  auto stage = [&](int kk) {
    char* At = lds + (kk & 1) * 32768;
    char* Bt = At + 16384;
    const int d0 = kk * 64;
#pragma unroll
    for (int i = 0; i < 4; ++i) {
      int s = i * 256 + tid;
      int row = s >> 3, c = (s & 7) ^ (row & 7);
      gll16(X + (long)(mt * 128 + row) * DIM + d0 + c * 8, At + i * 4096 + (wv << 10));
      gll16(W + (long)(nt * 128 + row) * DIM + d0 + c * 8, Bt + i * 4096 + (wv << 10));
    }
  };

  stage(0);
#pragma unroll 1
  for (int kk = 0; kk < 12; ++kk) {
    __syncthreads();
    if (kk + 1 < 12) stage(kk + 1);
    const char* At = lds + (kk & 1) * 32768;
    const char* Bt = At + 16384;
#pragma unroll
    for (int ks = 0; ks < 2; ++ks) {
      const int c = ks * 4 + l4;
      s16x8 a[4], b[4];
#pragma unroll
      for (int mi = 0; mi < 4; ++mi) {
        int row = (wv & 1) * 64 + mi * 16 + l15;
        a[mi] = *(const s16x8*)(At + row * 128 + ((c ^ (row & 7)) << 4));
      }
#pragma unroll
      for (int ni = 0; ni < 4; ++ni) {
        int row = (wv >> 1) * 64 + ni * 16 + l15;
        b[ni] = *(const s16x8*)(Bt + row * 128 + ((c ^ (row & 7)) << 4));
      }
#pragma unroll
      for (int mi = 0; mi < 4; ++mi)
#pragma unroll
        for (int ni = 0; ni < 4; ++ni)
          acc[mi][ni] = __builtin_amdgcn_mfma_f32_16x16x32_bf16(a[mi], b[ni], acc[mi][ni], 0, 0, 0);
    }
  }

#pragma unroll
  for (int mi = 0; mi < 4; ++mi)
#pragma unroll
    for (int ni = 0; ni < 4; ++ni) {
      int row0 = mt * 128 + (wv & 1) * 64 + mi * 16 + l4 * 4;
      int col = nt * 128 + (wv >> 1) * 64 + ni * 16 + l15;
      if (z == 2) {
        ushort4 r;
        r.x = f2bf(acc[mi][ni][0]); r.y = f2bf(acc[mi][ni][1]);
        r.z = f2bf(acc[mi][ni][2]); r.w = f2bf(acc[mi][ni][3]);
        *(ushort4*)(Vtb + (long)col * SEQ + row0) = r;  // V transposed: Vt[col][row]
      } else {
        unsigned short* dst = (z == 0) ? Qb : Kb;
#pragma unroll
        for (int g = 0; g < 4; ++g)
          dst[(long)(row0 + g) * DIM + col] = f2bf(acc[mi][ni][g]);
      }
    }
}

// ---------------- flash attention (R0-proven skeleton; exp-phase l; bf16 partials) ----
// BM=64 q rows/block, BN=256 keys/iter, 8 waves. All-16x16x32 (verified layouts only).
#define SCALE_LOG2E 0.05205878f  // (1/sqrt(768)) * log2(e)

__global__ __launch_bounds__(512, 2)
void flash_kernel(const unsigned short* __restrict__ Q,   // [8192][768] bf16
                  const unsigned short* __restrict__ K,   // [8192][768] bf16
                  const unsigned short* __restrict__ V,   // [768][8192] bf16 (transposed)
                  unsigned short* __restrict__ partp,     // [G][8192][768] bf16 (G-split mode)
                  float* __restrict__ outf,               // [8192][768] fp32 (norm mode)
                  float* __restrict__ lout,               // [G][8192] (G-split mode)
                  int kv_len, int norm_out) {
  // LDS: staging arena 80KB (QK bufs 2x40KB; PV bufs 2x32KB aliased) + P 32KB + l 1KB
  __shared__ __align__(16) char lds[80 * 1024 + 32 * 1024 + 1024];
  char* arena = lds;
  char* Pl = lds + 81920;
  float* l_part = (float*)(lds + 81920 + 32768);  // [4][64]

  const int tid = threadIdx.x;
  const int lane = tid & 63, wv = tid >> 6;
  const int l15 = lane & 15, l4 = lane >> 4;
  const int qtile = blockIdx.x, split = blockIdx.y;
  const long kv0 = (long)split * kv_len;
  const long qrow0 = (long)qtile * 64;
  const int R = wv & 1;   // S row-half
  const int C = wv >> 1;  // S key-quarter

  f32x4 acc_o[4][6];
  float acc_lp[8];
#pragma unroll
  for (int i = 0; i < 4; ++i)
#pragma unroll
    for (int j = 0; j < 6; ++j) acc_o[i][j] = f32x4{0.f, 0.f, 0.f, 0.f};
#pragma unroll
  for (int i = 0; i < 8; ++i) acc_lp[i] = 0.f;

  const int niter = kv_len >> 8;

#pragma unroll 1
  for (int it = 0; it < niter; ++it) {
    const long kb = kv0 + (long)it * 256;

    auto stageQK = [&](int r) {
      char* Qc = arena + (r & 1) * 40960;
      char* Kc = Qc + 8192;
      const int d0 = r * 64;
      {
        int s = tid;
        int row = s >> 3, c = (s & 7) ^ (row & 7);
        gll16(Q + (qrow0 + row) * DIM + d0 + c * 8, Qc + (wv << 10));
      }
#pragma unroll
      for (int i = 0; i < 4; ++i) {
        int s = i * 512 + tid;
        int row = s >> 3, c = (s & 7) ^ (row & 7);
        gll16(K + (kb + row) * DIM + d0 + c * 8, Kc + i * 8192 + (wv << 10));
      }
    };
    auto stagePV = [&](int r) {
      char* Vc = arena + (r & 1) * 32768;
      const int cc_ = r >> 2, kh_ = r & 3;
#pragma unroll
      for (int i = 0; i < 4; ++i) {
        int s = i * 512 + tid;
        int vr = s >> 3, c = (s & 7) ^ (vr & 7);
        gll16(V + (long)(cc_ * 256 + vr) * SEQ + kb + kh_ * 64 + c * 8, Vc + i * 8192 + (wv << 10));
      }
    };

    // ---- QK: S[64x256], per-wave region [32 rows x 64 keys] = 2x4 16x16 tiles ----
    f32x4 acc_s[2][4];
#pragma unroll
    for (int a = 0; a < 2; ++a)
#pragma unroll
      for (int b = 0; b < 4; ++b) acc_s[a][b] = f32x4{0.f, 0.f, 0.f, 0.f};

    stageQK(0);
#pragma unroll 1
    for (int r = 0; r < 12; ++r) {
      __syncthreads();  // drains round-r loads; all waves done with round r-1 compute
      if (r + 1 < 12) stageQK(r + 1);
      const char* Qc = arena + (r & 1) * 40960;
      const char* Kc = Qc + 8192;
#pragma unroll
      for (int ks = 0; ks < 2; ++ks) {
        const int c = ks * 4 + l4;
        s16x8 af[2], bk[4];
#pragma unroll
        for (int rt = 0; rt < 2; ++rt) {
          int row = R * 32 + rt * 16 + l15;
          af[rt] = *(const s16x8*)(Qc + row * 128 + ((c ^ (row & 7)) << 4));
        }
#pragma unroll
        for (int ct = 0; ct < 4; ++ct) {
          int kr = C * 64 + ct * 16 + l15;
          bk[ct] = *(const s16x8*)(Kc + kr * 128 + ((c ^ (kr & 7)) << 4));
        }
#pragma unroll
        for (int rt = 0; rt < 2; ++rt)
#pragma unroll
          for (int ct = 0; ct < 4; ++ct)
            acc_s[rt][ct] = __builtin_amdgcn_mfma_f32_16x16x32_bf16(af[rt], bk[ct], acc_s[rt][ct], 0, 0, 0);
      }
    }

    // ---- P = exp(S/sqrt(D)) -> bf16 -> LDS (swizzled [64][256]); per-lane l partials ----
#pragma unroll
    for (int rt = 0; rt < 2; ++rt)
#pragma unroll
      for (int ct = 0; ct < 4; ++ct)
#pragma unroll
        for (int g = 0; g < 4; ++g) {
          float p = exp2f(acc_s[rt][ct][g] * SCALE_LOG2E);
          acc_lp[rt * 4 + g] += p;
          int row = R * 32 + rt * 16 + l4 * 4 + g;
          int col = C * 64 + ct * 16 + l15;
          int off = row * 512 + ((((col >> 3) ^ (row & 7))) << 4) + ((col & 7) << 1);
          *(unsigned short*)(Pl + off) = f2bf(p);
        }

    // ---- PV: O[64x768] += P[64x256] @ V; wave w owns col-tiles {cc*16+w, cc*16+w+8} ----
    stagePV(0);
#pragma unroll
    for (int cc = 0; cc < 3; ++cc) {
#pragma unroll 1
      for (int kh = 0; kh < 4; ++kh) {
        const int r = cc * 4 + kh;
        __syncthreads();  // P visible (first round) + round-r V loaded + prev compute done
        if (r + 1 < 12) stagePV(r + 1);
        const char* Vc = arena + (r & 1) * 32768;
#pragma unroll
        for (int ks = 0; ks < 2; ++ks) {
          s16x8 pa[4], vb[2];
          const int ck = kh * 8 + ks * 4 + l4;
#pragma unroll
          for (int rs = 0; rs < 4; ++rs) {
            int row = rs * 16 + l15;
            int pc = (ck & ~7) | ((ck & 7) ^ (row & 7));
            pa[rs] = *(const s16x8*)(Pl + row * 512 + (pc << 4));
          }
          const int cv = ks * 4 + l4;
#pragma unroll
          for (int t = 0; t < 2; ++t) {
            int vr = (wv + 8 * t) * 16 + l15;
            vb[t] = *(const s16x8*)(Vc + vr * 128 + ((cv ^ (vr & 7)) << 4));
          }
#pragma unroll
          for (int rs = 0; rs < 4; ++rs)
#pragma unroll
            for (int t = 0; t < 2; ++t)
              acc_o[rs][cc * 2 + t] =
                  __builtin_amdgcn_mfma_f32_16x16x32_bf16(pa[rs], vb[t], acc_o[rs][cc * 2 + t], 0, 0, 0);
        }
      }
    }
    __syncthreads();  // Vc/P consumed before next iter's staging / P rewrite
  }

  // ---- l reduction: butterfly over lane bits 0..3 (16 cols/group), combine quarters ----
#pragma unroll
  for (int i = 0; i < 8; ++i) {
    float v = acc_lp[i];
    v += __shfl_xor(v, 1); v += __shfl_xor(v, 2);
    v += __shfl_xor(v, 4); v += __shfl_xor(v, 8);
    acc_lp[i] = v;
  }
  if (l15 == 0) {
#pragma unroll
    for (int rt = 0; rt < 2; ++rt)
#pragma unroll
      for (int g = 0; g < 4; ++g)
        l_part[C * 64 + R * 32 + rt * 16 + l4 * 4 + g] = acc_lp[rt * 4 + g];
  }
  __syncthreads();

  if (!norm_out) {
    if (tid < 64)
      lout[(long)split * SEQ + qrow0 + tid] =
          l_part[tid] + l_part[64 + tid] + l_part[128 + tid] + l_part[192 + tid];
#pragma unroll
    for (int rt = 0; rt < 4; ++rt) {
      int row = rt * 16 + l4 * 4;
#pragma unroll
      for (int j = 0; j < 6; ++j) {
        int cc = j >> 1, t = j & 1;
        int col = (cc * 16 + wv + 8 * t) * 16 + l15;
#pragma unroll
        for (int g = 0; g < 4; ++g)
          partp[(long)split * SEQ * DIM + (qrow0 + row + g) * DIM + col] = f2bf(acc_o[rt][j][g]);
      }
    }
  } else {
    float linv[4][4];
#pragma unroll
    for (int rt = 0; rt < 4; ++rt)
#pragma unroll
      for (int g = 0; g < 4; ++g) {
        int row = rt * 16 + l4 * 4 + g;
        linv[rt][g] = 1.0f / (l_part[row] + l_part[64 + row] + l_part[128 + row] + l_part[192 + row]);
      }
#pragma unroll
    for (int rt = 0; rt < 4; ++rt) {
      int row = rt * 16 + l4 * 4;
#pragma unroll
      for (int j = 0; j < 6; ++j) {
        int cc = j >> 1, t = j & 1;
        int col = (cc * 16 + wv + 8 * t) * 16 + l15;
#pragma unroll
        for (int g = 0; g < 4; ++g)
          outf[(qrow0 + row + g) * DIM + col] = acc_o[rt][j][g] * linv[rt][g];
      }
    }
  }
}

// ---------------- combine (G=2): out = (p0+p1)/(l0+l1), partials bf16 ----------------
__global__ void combine_kernel(const unsigned short* __restrict__ part,
                               const float* __restrict__ lsum,
                               float* __restrict__ out, int n4) {
  int i = blockIdx.x * blockDim.x + threadIdx.x;
  if (i >= n4) return;
  int row = (i * 4) / DIM;
  ushort4 p0 = ((const ushort4*)part)[i];
  ushort4 p1 = ((const ushort4*)(part + (long)SEQ * DIM))[i];
  float inv = 1.0f / (lsum[row] + lsum[SEQ + row]);
  float4 o;
  o.x = (bf2f(p0.x) + bf2f(p1.x)) * inv;
  o.y = (bf2f(p0.y) + bf2f(p1.y)) * inv;
  o.z = (bf2f(p0.z) + bf2f(p1.z)) * inv;
  o.w = (bf2f(p0.w) + bf2f(p1.w)) * inv;
  ((float4*)out)[i] = o;
}

// ---------------- host ----------------
extern "C" void kernel_launch(void* const* d_in, const int* in_sizes, int n_in,
                              void* d_out, int out_size, void* d_ws, size_t ws_size,
                              hipStream_t stream) {
  const float* x = (const float*)d_in[0];
  const float* wq = (const float*)d_in[1];
  const float* wk = (const float*)d_in[2];
  const float* wv = (const float*)d_in[3];
  float* out = (float*)d_out;
  char* ws = (char*)d_ws;

  const size_t o_xbf = 0;
  const size_t o_wq = o_xbf + (size_t)SEQ * DIM * 2;
  const size_t o_wk = o_wq + (size_t)DIM * DIM * 2;
  const size_t o_wv = o_wk + (size_t)DIM * DIM * 2;
  const size_t o_q = o_wv + (size_t)DIM * DIM * 2;
  const size_t o_k = o_q + (size_t)SEQ * DIM * 2;
  const size_t o_vt = o_k + (size_t)SEQ * DIM * 2;
  const size_t o_part = o_vt + (size_t)SEQ * DIM * 2;
  const size_t o_l = o_part + (size_t)2 * SEQ * DIM * 2;   // bf16 partials
  const size_t total_g2 = o_l + (size_t)2 * SEQ * 4;

  unsigned short* Xbf = (unsigned short*)(ws + o_xbf);
  unsigned short* Wqb = (unsigned short*)(ws + o_wq);
  unsigned short* Wkb = (unsigned short*)(ws + o_wk);
  unsigned short* Wvb = (unsigned short*)(ws + o_wv);
  unsigned short* Qb = (unsigned short*)(ws + o_q);
  unsigned short* Kb = (unsigned short*)(ws + o_k);
  unsigned short* Vtb = (unsigned short*)(ws + o_vt);
  unsigned short* part = (unsigned short*)(ws + o_part);
  float* lbuf = (float*)(ws + o_l);

  const int G = (ws_size >= total_g2) ? 2 : 1;

  cast_all_kernel<<<7872, 256, 0, stream>>>(x, wq, wk, wv, Xbf, Wqb, Wkb, Wvb);
  proj_kernel<<<dim3(64, 6, 3), 256, 0, stream>>>(Xbf, Wqb, Wkb, Wvb, Qb, Kb, Vtb);
  if (G == 2) {
    flash_kernel<<<dim3(128, 2), 512, 0, stream>>>(Qb, Kb, Vtb, part, nullptr, lbuf, SEQ / 2, 0);
    combine_kernel<<<6144, 256, 0, stream>>>(part, lbuf, out, SEQ * DIM / 4);
  } else {
    flash_kernel<<<dim3(128, 1), 512, 0, stream>>>(Qb, Kb, Vtb, nullptr, out, nullptr, SEQ, 1);
  }
}